// Round 18
// baseline (319.678 us; speedup 1.0000x reference)
//
#include <hip/hip_runtime.h>
#include <cstddef>

#define DM 192
#define DI 384
#define DS 16
#define DR 12
#define L 1024
#define ROWS 4096   // B*N = 4*1024
#define SEG 32      // time segments for two-pass scan
#define ST  32      // steps per segment
#define LOG2E 1.4426950408889634f

typedef unsigned short ushortx;
typedef short bf16x8 __attribute__((ext_vector_type(8)));
typedef float f32x4  __attribute__((ext_vector_type(4)));

// ---------------- helpers ----------------
__device__ __forceinline__ float wave_sum(float v) {
  #pragma unroll
  for (int off = 32; off > 0; off >>= 1) v += __shfl_xor(v, off);
  return v;
}

__device__ __forceinline__ ushortx f2bf(float x) {   // fp32 -> bf16 RNE
  unsigned u = __float_as_uint(x);
  u += 0x7fffu + ((u >> 16) & 1u);
  return (ushortx)(u >> 16);
}
__device__ __forceinline__ float bf2f(ushortx u) {
  return __uint_as_float(((unsigned)u) << 16);
}

// row permutation within each batch's 1024 rows
__device__ __forceinline__ int map_row(int t, int mode) {
  switch (mode) {
    case 1: return 1023 - t;                                   // flip
    case 2: return ((t & 31) << 5) | (t >> 5);                 // 32x32 transpose
    case 3: { int u = 1023 - t; return ((u & 31) << 5) | (u >> 5); } // perm(flip)
    case 4: return 1023 - (((t & 31) << 5) | (t >> 5));        // flip(perm)
    default: return t;
  }
}

// ---------------- prep: wcvt(y<6) / in_wT(y==6) / input LN(y==7) / bC(y==8) -------------
struct WcvtArgs {
  const float* src[6];
  unsigned int off[6];   // dst offset in shorts
  unsigned int n[6];     // element count
};
__global__ __launch_bounds__(256) void prep_kernel(
    WcvtArgs a, ushortx* __restrict__ dst,
    const float* __restrict__ in_w, unsigned int_off,
    const float* __restrict__ in_b, float* __restrict__ bC,
    const float* __restrict__ x, const float* __restrict__ g,
    const float* __restrict__ b, float* __restrict__ xs, ushortx* __restrict__ xs_bf)
{
  int y = blockIdx.y;
  if (y < 6) {
    int i = (blockIdx.x * 256 + threadIdx.x) * 4;
    if (i < (int)a.n[y]) {
      float4 v = *(const float4*)(a.src[y] + i);
      ushort4 o;
      o.x = f2bf(v.x); o.y = f2bf(v.y); o.z = f2bf(v.z); o.w = f2bf(v.w);
      *(ushort4*)(dst + a.off[y] + i) = o;
    }
    return;
  }
  if (y == 6) {   // in_wT[n][j] = in_w[j][n]; 192*192
    int i = blockIdx.x * 256 + threadIdx.x;
    if (i < DM * DM) {
      int n = i / DM, j = i % DM;
      dst[int_off + i] = f2bf(in_w[(size_t)j * DM + n]);
    }
    return;
  }
  if (y == 8) {   // bC[k][n] = sum_j Win_k[n][j] * in_b[j];  4*768
    int idx = blockIdx.x * 256 + threadIdx.x;
    if (idx < 4 * 768) {
      int k = idx / 768, n = idx % 768;
      const float* wr = a.src[0] + (size_t)k * 768 * DM + (size_t)n * DM;  // m_in_w
      float acc = 0.f;
      for (int j = 0; j < DM; ++j) acc = fmaf(wr[j], in_b[j], acc);
      bC[idx] = acc;
    }
    return;
  }
  // ---- y==7: input layernorm + transpose ----
  if (blockIdx.x >= 1024) return;
  int wave = threadIdx.x >> 6;
  int lane = threadIdx.x & 63;
  int r = blockIdx.x * 4 + wave;          // b*1024 + n
  int bb = r >> 10, n = r & 1023;
  const float* xb = x + (size_t)bb * DM * L + n;
  float v[3];
  float s = 0.f, s2 = 0.f;
  #pragma unroll
  for (int j = 0; j < 3; ++j) {
    int c = lane + j * 64;
    v[j] = xb[(size_t)c * L];
    s += v[j]; s2 += v[j] * v[j];
  }
  s = wave_sum(s); s2 = wave_sum(s2);
  float mean = s * (1.f / DM);
  float var  = s2 * (1.f / DM) - mean * mean;
  float rstd = rsqrtf(var + 1e-5f);
  float* xo = xs + (size_t)r * DM;
  ushortx* xob = xs_bf + (size_t)r * DM;
  #pragma unroll
  for (int j = 0; j < 3; ++j) {
    int c = lane + j * 64;
    float val = (v[j] - mean) * rstd * g[c] + b[c];
    xo[c] = val;
    xob[c] = f2bf(val);
  }
}

// ---------------- full-K-preload GEMM: all NIT*2 loads in flight at t=0 -----------------
// BM=BN=64, K = NIT*32 (<=12 slabs); N multiple of 64 (no guard); bf16 out.
template <int NIT>
__global__ __launch_bounds__(256) void gemm_fullk_kernel(
    const ushortx* __restrict__ A, int lda, const ushortx* __restrict__ W,
    const float* __restrict__ bias, ushortx* __restrict__ Cb,
    int ldc, int coff, int4 perm,
    long astride, long wstride, long cstride, int coffstride, int bstride)
{
  __shared__ __align__(16) short As[2][64][40];
  __shared__ __align__(16) short Bs[2][64][40];

  int z = blockIdx.z;
  A += (size_t)z * astride;
  W += (size_t)z * wstride;
  Cb += (size_t)z * cstride;
  if (bias) bias += (size_t)z * bstride;
  int permMode = (z == 0) ? perm.x : (z == 1) ? perm.y : (z == 2) ? perm.z : perm.w;
  int co = coff + z * coffstride;
  const int K = NIT * 32;

  int tid = threadIdx.x;
  int m0 = blockIdx.x * 64;
  int n0 = blockIdx.y * 64;

  int ar = tid >> 2, ak = (tid & 3) * 8;
  int arow = m0 + ar;
  int amrow = (arow & ~1023) | map_row(arow & 1023, permMode);
  const ushortx* ap = A + (size_t)amrow * lda + ak;
  const ushortx* wp = W + (size_t)(n0 + ar) * K + ak;

  int lane = tid & 63;
  int w = tid >> 6, wm = w >> 1, wn = w & 1;
  int lm = lane & 15, lq = lane >> 4;

  bf16x8 rA[NIT], rB[NIT];
  #pragma unroll
  for (int ki = 0; ki < NIT; ++ki) rA[ki] = *(const bf16x8*)(ap + ki * 32);
  #pragma unroll
  for (int ki = 0; ki < NIT; ++ki) rB[ki] = *(const bf16x8*)(wp + ki * 32);

  f32x4 acc[2][2];
  #pragma unroll
  for (int i = 0; i < 2; ++i)
    #pragma unroll
    for (int j = 0; j < 2; ++j) acc[i][j] = (f32x4){0.f, 0.f, 0.f, 0.f};

  *(bf16x8*)&As[0][ar][ak] = rA[0];
  *(bf16x8*)&Bs[0][ar][ak] = rB[0];
  __syncthreads();

  #pragma unroll
  for (int ki = 0; ki < NIT; ++ki) {
    int cur = ki & 1;
    bf16x8 fa[2], fb[2];
    #pragma unroll
    for (int i = 0; i < 2; ++i)
      fa[i] = *(const bf16x8*)&As[cur][wm * 32 + i * 16 + lm][lq * 8];
    #pragma unroll
    for (int j = 0; j < 2; ++j)
      fb[j] = *(const bf16x8*)&Bs[cur][wn * 32 + j * 16 + lm][lq * 8];
    #pragma unroll
    for (int i = 0; i < 2; ++i)
      #pragma unroll
      for (int j = 0; j < 2; ++j)
        acc[i][j] = __builtin_amdgcn_mfma_f32_16x16x32_bf16(fa[i], fb[j], acc[i][j], 0, 0, 0);
    if (ki + 1 < NIT) {
      int nxt = cur ^ 1;
      *(bf16x8*)&As[nxt][ar][ak] = rA[ki + 1];
      *(bf16x8*)&Bs[nxt][ar][ak] = rB[ki + 1];
      __syncthreads();
    }
  }

  #pragma unroll
  for (int i = 0; i < 2; ++i) {
    #pragma unroll
    for (int r = 0; r < 4; ++r) {
      int row = m0 + wm * 32 + i * 16 + lq * 4 + r;
      #pragma unroll
      for (int j = 0; j < 2; ++j) {
        int n = n0 + wn * 32 + j * 16 + lm;
        float v = acc[i][j][r];
        if (bias) v += bias[n];
        Cb[(size_t)row * ldc + co + n] = f2bf(v);
      }
    }
  }
}

// ---------------- bf16 MFMA GEMM: double-buffered, register-prefetched K-loop ----------
template <int BM, int BN>
__global__ __launch_bounds__(256) void gemm_kernel(
    const ushortx* __restrict__ A, int lda, const ushortx* __restrict__ W,
    const float* __restrict__ bias, float* __restrict__ C, ushortx* __restrict__ Cb,
    int N, int K, int ldc, int coff, int4 perm, int act,
    long astride, long wstride, long cstride, int coffstride, int bstride)
{
  constexpr int MF = BM / 32;
  constexpr int NF = BN / 32;
  constexpr int AR = (BM * 32) / (256 * 8);
  constexpr int BR = (BN * 32) / (256 * 8);
  __shared__ __align__(16) short As[2][BM][40];
  __shared__ __align__(16) short Bs[2][BN][40];

  int z = blockIdx.z;
  A += (size_t)z * astride;
  W += (size_t)z * wstride;
  if (C)  C  += (size_t)z * cstride;
  if (Cb) Cb += (size_t)z * cstride;
  if (bias) bias += (size_t)z * bstride;
  int permMode = (z == 0) ? perm.x : (z == 1) ? perm.y : (z == 2) ? perm.z : perm.w;
  int co = coff + z * coffstride;

  int tid = threadIdx.x;
  int m0 = blockIdx.x * BM;
  int n0 = blockIdx.y * BN;

  int ar, ak;
  if (AR == 2) { ar = tid >> 1; ak = (tid & 1) * 16; }
  else         { ar = tid >> 2; ak = (tid & 3) * 8; }
  int arow = m0 + ar;
  int amrow = (arow & ~1023) | map_row(arow & 1023, permMode);
  const ushortx* ap = A + (size_t)amrow * lda + ak;

  int bn, bk;
  if (BR == 2) { bn = tid >> 1; bk = (tid & 1) * 16; }
  else         { bn = tid >> 2; bk = (tid & 3) * 8; }
  const ushortx* wp = W + (size_t)(n0 + bn) * K + bk;
  bool bok = (n0 + bn) < N;

  int lane = tid & 63;
  int w = tid >> 6, wm = w >> 1, wn = w & 1;
  int lm = lane & 15, lq = lane >> 4;

  f32x4 acc[MF][NF];
  #pragma unroll
  for (int i = 0; i < MF; ++i)
    #pragma unroll
    for (int j = 0; j < NF; ++j) acc[i][j] = (f32x4){0.f, 0.f, 0.f, 0.f};

  const bf16x8 zz = {0, 0, 0, 0, 0, 0, 0, 0};
  bf16x8 ra[AR], rb[BR];

  #pragma unroll
  for (int u = 0; u < AR; ++u) ra[u] = *(const bf16x8*)(ap + u * 8);
  #pragma unroll
  for (int u = 0; u < BR; ++u) rb[u] = bok ? *(const bf16x8*)(wp + u * 8) : zz;
  #pragma unroll
  for (int u = 0; u < AR; ++u) *(bf16x8*)&As[0][ar][ak + u * 8] = ra[u];
  #pragma unroll
  for (int u = 0; u < BR; ++u) *(bf16x8*)&Bs[0][bn][bk + u * 8] = rb[u];
  __syncthreads();

  int niter = K >> 5;
  for (int ki = 0; ki < niter; ++ki) {
    int cur = ki & 1;
    if (ki + 1 < niter) {
      int k0 = (ki + 1) * 32;
      #pragma unroll
      for (int u = 0; u < AR; ++u) ra[u] = *(const bf16x8*)(ap + k0 + u * 8);
      #pragma unroll
      for (int u = 0; u < BR; ++u) rb[u] = bok ? *(const bf16x8*)(wp + k0 + u * 8) : zz;
    }
    bf16x8 fa[MF], fb[NF];
    #pragma unroll
    for (int i = 0; i < MF; ++i)
      fa[i] = *(const bf16x8*)&As[cur][wm * (BM / 2) + i * 16 + lm][lq * 8];
    #pragma unroll
    for (int j = 0; j < NF; ++j)
      fb[j] = *(const bf16x8*)&Bs[cur][wn * (BN / 2) + j * 16 + lm][lq * 8];
    #pragma unroll
    for (int i = 0; i < MF; ++i)
      #pragma unroll
      for (int j = 0; j < NF; ++j)
        acc[i][j] = __builtin_amdgcn_mfma_f32_16x16x32_bf16(fa[i], fb[j], acc[i][j], 0, 0, 0);
    if (ki + 1 < niter) {
      int nxt = cur ^ 1;
      #pragma unroll
      for (int u = 0; u < AR; ++u) *(bf16x8*)&As[nxt][ar][ak + u * 8] = ra[u];
      #pragma unroll
      for (int u = 0; u < BR; ++u) *(bf16x8*)&Bs[nxt][bn][bk + u * 8] = rb[u];
      __syncthreads();
    }
  }

  #pragma unroll
  for (int i = 0; i < MF; ++i) {
    #pragma unroll
    for (int r = 0; r < 4; ++r) {
      int row = m0 + wm * (BM / 2) + i * 16 + lq * 4 + r;
      #pragma unroll
      for (int j = 0; j < NF; ++j) {
        int n = n0 + wn * (BN / 2) + j * 16 + lm;
        if (n < N) {
          float v = acc[i][j][r];
          if (bias) v += bias[n];
          if (act == 1) v = 0.5f * v * (1.f + erff(v * 0.70710678118f));
          if (C)  C [(size_t)row * ldc + co + n] = v;
          if (Cb) Cb[(size_t)row * ldc + co + n] = f2bf(v);
        }
      }
    }
  }
}

// ---------------- fused: out = LN(h2 @ o_w^T + o_b) + xs, transposed store -------------
__global__ __launch_bounds__(256) void gemm_ln_kernel(
    const ushortx* __restrict__ A, const ushortx* __restrict__ W,
    const float* __restrict__ ob, const float* __restrict__ g,
    const float* __restrict__ b, const float* __restrict__ xs,
    float* __restrict__ out)
{
  __shared__ __align__(16) char smem[64 * 200 * 4];
  short* As0 = (short*)smem;              // 64*40
  short* As1 = As0 + 64 * 40;
  short* Bs0 = As1 + 64 * 40;             // 192*40
  short* Bs1 = Bs0 + 192 * 40;
  float* Ct  = (float*)smem;              // 64*200 (after barrier; aliases As/Bs)

  int tid = threadIdx.x;
  int m0 = blockIdx.x * 64;

  int ar = tid >> 2, ak = (tid & 3) * 8;
  const ushortx* ap = A + (size_t)(m0 + ar) * DM + ak;

  int lane = tid & 63;
  int w = tid >> 6, wm = w >> 1, wn = w & 1;
  int lm = lane & 15, lq = lane >> 4;

  f32x4 acc[2][6];
  #pragma unroll
  for (int i = 0; i < 2; ++i)
    #pragma unroll
    for (int j = 0; j < 6; ++j) acc[i][j] = (f32x4){0.f, 0.f, 0.f, 0.f};

  bf16x8 ra, rb[3];
  ra = *(const bf16x8*)ap;
  #pragma unroll
  for (int u = 0; u < 3; ++u) {
    int c = tid + u * 256;
    rb[u] = *(const bf16x8*)(W + (size_t)(c >> 2) * DM + (c & 3) * 8);
  }
  *(bf16x8*)&As0[ar * 40 + ak] = ra;
  #pragma unroll
  for (int u = 0; u < 3; ++u) {
    int c = tid + u * 256;
    *(bf16x8*)&Bs0[(c >> 2) * 40 + (c & 3) * 8] = rb[u];
  }
  __syncthreads();

  const int niter = DM / 32;   // 6
  for (int ki = 0; ki < niter; ++ki) {
    short* Ac = (ki & 1) ? As1 : As0;
    short* Bc = (ki & 1) ? Bs1 : Bs0;
    if (ki + 1 < niter) {
      int k0 = (ki + 1) * 32;
      ra = *(const bf16x8*)(ap + k0);
      #pragma unroll
      for (int u = 0; u < 3; ++u) {
        int c = tid + u * 256;
        rb[u] = *(const bf16x8*)(W + (size_t)(c >> 2) * DM + (c & 3) * 8 + k0);
      }
    }
    bf16x8 fa[2], fb[6];
    #pragma unroll
    for (int i = 0; i < 2; ++i)
      fa[i] = *(const bf16x8*)&Ac[(wm * 32 + i * 16 + lm) * 40 + lq * 8];
    #pragma unroll
    for (int j = 0; j < 6; ++j)
      fb[j] = *(const bf16x8*)&Bc[(wn * 96 + j * 16 + lm) * 40 + lq * 8];
    #pragma unroll
    for (int i = 0; i < 2; ++i)
      #pragma unroll
      for (int j = 0; j < 6; ++j)
        acc[i][j] = __builtin_amdgcn_mfma_f32_16x16x32_bf16(fa[i], fb[j], acc[i][j], 0, 0, 0);
    if (ki + 1 < niter) {
      short* An = (ki & 1) ? As0 : As1;
      short* Bn = (ki & 1) ? Bs0 : Bs1;
      *(bf16x8*)&An[ar * 40 + ak] = ra;
      #pragma unroll
      for (int u = 0; u < 3; ++u) {
        int c = tid + u * 256;
        *(bf16x8*)&Bn[(c >> 2) * 40 + (c & 3) * 8] = rb[u];
      }
    }
    __syncthreads();
  }

  #pragma unroll
  for (int i = 0; i < 2; ++i) {
    #pragma unroll
    for (int r = 0; r < 4; ++r) {
      int row = wm * 32 + i * 16 + lq * 4 + r;
      #pragma unroll
      for (int j = 0; j < 6; ++j) {
        int col = wn * 96 + j * 16 + lm;
        Ct[row * 200 + col] = acc[i][j][r] + ob[col];
      }
    }
  }
  __syncthreads();

  int row = tid >> 2, p = tid & 3;
  const float* base = Ct + row * 200 + p * 48;
  float s = 0.f, s2 = 0.f;
  #pragma unroll
  for (int c = 0; c < 48; ++c) { float v = base[c]; s += v; s2 += v * v; }
  s  += __shfl_xor(s, 1);  s  += __shfl_xor(s, 2);
  s2 += __shfl_xor(s2, 1); s2 += __shfl_xor(s2, 2);
  float mean = s * (1.f / DM);
  float var  = s2 * (1.f / DM) - mean * mean;
  float rstd = rsqrtf(var + 1e-5f);
  int gr = m0 + row, bb = gr >> 10, n = gr & 1023;
  const float* xsr = xs + (size_t)gr * DM + p * 48;
  float* op = out + (size_t)bb * DM * L + n;
  #pragma unroll
  for (int c48 = 0; c48 < 48; ++c48) {
    int c = p * 48 + c48;
    float val = (base[c48] - mean) * rstd * g[c] + b[c] + xsr[c48];
    op[(size_t)c * L] = val;
  }
}

// ---------------- depthwise causal conv (k=4) + bias + silu: 4 t per thread ------------
__global__ __launch_bounds__(256) void conv_silu_kernel(
    const ushortx* __restrict__ xz, const float* __restrict__ cw,
    const float* __restrict__ cb, ushortx* __restrict__ xsm_bf)
{
  int idx = blockIdx.x * 256 + threadIdx.x;   // 16*256*384 total
  int d = idx % DI;
  int rest = idx / DI;
  int tq = rest & 255;
  int seq = rest >> 8;
  int k = seq >> 2;
  int t0 = tq * 4;
  const ushortx* xh = xz + (size_t)seq * L * (2 * DI) + d;
  const float* w = cw + ((size_t)k * DI + d) * 4;
  float w0 = w[0], w1 = w[1], w2 = w[2], w3 = w[3];
  float bias = cb[k * DI + d];
  float in[7];
  #pragma unroll
  for (int j = 0; j < 7; ++j) {
    int t = t0 - 3 + j;
    in[j] = (t >= 0) ? bf2f(xh[(size_t)t * (2 * DI)]) : 0.f;
  }
  ushortx* yo = xsm_bf + ((size_t)seq * L + t0) * DI + d;
  #pragma unroll
  for (int i = 0; i < 4; ++i) {
    float acc = bias;
    acc = fmaf(w0, in[i],     acc);
    acc = fmaf(w1, in[i + 1], acc);
    acc = fmaf(w2, in[i + 2], acc);
    acc = fmaf(w3, in[i + 3], acc);
    float sig = 1.f / (1.f + __expf(-acc));
    yo[(size_t)i * DI] = f2bf(acc * sig);
  }
}

// ---------------- dt = softplus(dbl[:, :12] @ Wdt^T + bdt) -> bf16 ----------------
__global__ __launch_bounds__(256) void dt_kernel(
    const float* __restrict__ dbl, const float* __restrict__ Wdt,
    const float* __restrict__ bdt, ushortx* __restrict__ dt)
{
  int idx = blockIdx.x * 256 + threadIdx.x;   // 16*1024*384
  int d = idx % DI;
  int row = idx / DI;        // seq*1024 + t
  int k = row >> 12;
  const float* dl = dbl + (size_t)row * 44;
  const float* w = Wdt + ((size_t)k * DI + d) * DR;
  float acc = bdt[k * DI + d];
  #pragma unroll
  for (int r = 0; r < DR; ++r) acc = fmaf(w[r], dl[r], acc);
  float v = (acc > 20.f) ? acc : log1pf(__expf(acc));
  dt[idx] = f2bf(v);
}

// ---------------- scan pass 1: per-segment partial scan (exp2-folded A) ----------------
__global__ __launch_bounds__(64) void scan_pass1(
    const float* __restrict__ dbl, const ushortx* __restrict__ dt,
    const ushortx* __restrict__ xsm_bf, const float* __restrict__ Alog,
    float* __restrict__ hseg, float* __restrict__ Sseg)
{
  __shared__ __align__(16) float sB[ST][16];
  int seq = blockIdx.y, g = blockIdx.z, k = seq >> 2;
  int d = blockIdx.x * 64 + threadIdx.x;

  const float* bbase = dbl + ((size_t)seq * L + g * ST) * 44 + 12;
  #pragma unroll
  for (int j = 0; j < 2; ++j) {
    int i = threadIdx.x + j * 64;
    int t = i >> 2, q = (i & 3) * 4;
    *(float4*)&sB[t][q] = *(const float4*)(bbase + (size_t)t * 44 + q);
  }
  float A[16];   // pre-scaled by log2e: dA = exp2(dtv * A[s])
  const float* alp = Alog + ((size_t)k * DI + d) * DS;
  #pragma unroll
  for (int s = 0; s < 16; ++s) A[s] = -__expf(alp[s]) * LOG2E;

  const ushortx* dtp = dt     + ((size_t)seq * L + g * ST) * DI + d;
  const ushortx* xp  = xsm_bf + ((size_t)seq * L + g * ST) * DI + d;
  __syncthreads();

  float h[16];
  #pragma unroll
  for (int s = 0; s < 16; ++s) h[s] = 0.f;
  float sdt = 0.f;
  float rDt[4], rX[4];
  #pragma unroll
  for (int j = 0; j < 4; ++j) {
    rDt[j] = bf2f(dtp[(size_t)j * DI]);
    rX [j] = bf2f(xp [(size_t)j * DI]);
  }

  #pragma unroll 4
  for (int t = 0; t < ST; ++t) {
    float dtv = rDt[t & 3], xv = rX[t & 3];
    if (t + 4 < ST) {
      rDt[t & 3] = bf2f(dtp[(size_t)(t + 4) * DI]);
      rX [t & 3] = bf2f(xp [(size_t)(t + 4) * DI]);
    }
    float dtx = dtv * xv;
    sdt += dtv;
    #pragma unroll
    for (int s = 0; s < 16; ++s) {
      float dA = exp2f(dtv * A[s]);
      h[s] = fmaf(dA, h[s], dtx * sB[t][s]);
    }
  }
  float* hp = hseg + (((size_t)seq * SEG + g) * DI + d) * DS;
  #pragma unroll
  for (int s = 0; s < 16; ++s) hp[s] = h[s];
  Sseg[((size_t)seq * SEG + g) * DI + d] = sdt;
}

// ---------------- scan mid: serial fold with 1-deep prefetch; hseg in place --------------
__global__ __launch_bounds__(64) void scan_mid(
    float* __restrict__ hseg, const float* __restrict__ Sseg,
    const float* __restrict__ Alog)
{
  int seq = blockIdx.y, k = seq >> 2;
  int d = blockIdx.x * 64 + threadIdx.x;
  float A[16];   // pre-scaled by log2e
  const float* alp = Alog + ((size_t)k * DI + d) * DS;
  #pragma unroll
  for (int s = 0; s < 16; ++s) A[s] = -__expf(alp[s]) * LOG2E;
  float h[16];
  #pragma unroll
  for (int s = 0; s < 16; ++s) h[s] = 0.f;

  // prefetch segment 0
  float nh[16], nS;
  {
    const float* hp0 = hseg + ((size_t)seq * SEG * DI + d) * DS;
    #pragma unroll
    for (int s = 0; s < 16; ++s) nh[s] = hp0[s];
    nS = Sseg[(size_t)seq * SEG * DI + d];
  }
  for (int g = 0; g < SEG; ++g) {
    float ch[16], cS = nS;
    #pragma unroll
    for (int s = 0; s < 16; ++s) ch[s] = nh[s];
    if (g + 1 < SEG) {        // prefetch next segment while folding current
      const float* hpn = hseg + (((size_t)seq * SEG + g + 1) * DI + d) * DS;
      #pragma unroll
      for (int s = 0; s < 16; ++s) nh[s] = hpn[s];
      nS = Sseg[((size_t)seq * SEG + g + 1) * DI + d];
    }
    float* hp = hseg + (((size_t)seq * SEG + g) * DI + d) * DS;
    #pragma unroll
    for (int s = 0; s < 16; ++s) hp[s] = h[s];           // corrected init for seg g
    #pragma unroll
    for (int s = 0; s < 16; ++s)
      h[s] = fmaf(h[s], exp2f(A[s] * cS), ch[s]);        // advance past seg g
  }
}

// ---------------- scan pass 2: init from hseg + scan + D skip + gate (exp2-folded) -------
__global__ __launch_bounds__(64) void scan_pass2(
    const float* __restrict__ dbl, const ushortx* __restrict__ dt,
    const ushortx* __restrict__ xz,
    ushortx* __restrict__ xy,       // x in / y out (in place)
    const float* __restrict__ Alog, const float* __restrict__ Dp,
    const float* __restrict__ hseg)
{
  __shared__ __align__(16) float sBC[ST][32];
  int seq = blockIdx.y, g = blockIdx.z, k = seq >> 2;
  int d = blockIdx.x * 64 + threadIdx.x;

  const float* bcbase = dbl + ((size_t)seq * L + g * ST) * 44 + 12;
  #pragma unroll
  for (int j = 0; j < 4; ++j) {
    int i = threadIdx.x + j * 64;
    int t = i >> 3, q = (i & 7) * 4;
    *(float4*)&sBC[t][q] = *(const float4*)(bcbase + (size_t)t * 44 + q);
  }
  float A[16];   // pre-scaled by log2e
  const float* alp = Alog + ((size_t)k * DI + d) * DS;
  #pragma unroll
  for (int s = 0; s < 16; ++s) A[s] = -__expf(alp[s]) * LOG2E;
  float Dv = Dp[k * DI + d];

  float h[16];
  {
    const float* hp = hseg + (((size_t)seq * SEG + g) * DI + d) * DS;
    #pragma unroll
    for (int s = 0; s < 16; ++s) h[s] = hp[s];
  }

  const ushortx* dtp = dt + ((size_t)seq * L + g * ST) * DI + d;
  const ushortx* zp  = xz + ((size_t)seq * L + g * ST) * (2 * DI) + DI + d;
  ushortx*       yp  = xy + ((size_t)seq * L + g * ST) * DI + d;
  __syncthreads();

  float rDt[4], rX[4], rZ[4];
  #pragma unroll
  for (int j = 0; j < 4; ++j) {
    rDt[j] = bf2f(dtp[(size_t)j * DI]);
    rX [j] = bf2f(yp [(size_t)j * DI]);
    rZ [j] = bf2f(zp [(size_t)j * (2 * DI)]);
  }

  #pragma unroll 4
  for (int t = 0; t < ST; ++t) {
    float dtv = rDt[t & 3], xv = rX[t & 3], zv = rZ[t & 3];
    if (t + 4 < ST) {
      rDt[t & 3] = bf2f(dtp[(size_t)(t + 4) * DI]);
      rX [t & 3] = bf2f(yp [(size_t)(t + 4) * DI]);
      rZ [t & 3] = bf2f(zp [(size_t)(t + 4) * (2 * DI)]);
    }
    float dtx = dtv * xv;
    float y = 0.f;
    #pragma unroll
    for (int s = 0; s < 16; ++s) {
      float dA = exp2f(dtv * A[s]);
      h[s] = fmaf(dA, h[s], dtx * sBC[t][s]);
      y = fmaf(h[s], sBC[t][16 + s], y);
    }
    y = fmaf(Dv, xv, y);
    float sig = 1.f / (1.f + __expf(-zv));
    yp[(size_t)t * DI] = f2bf(y * (zv * sig));
  }
}

// ---------------- host side ----------------
template <int BM, int BN>
static inline void gemm(const ushortx* A, int lda, const ushortx* W, const float* bias,
                        float* C, ushortx* Cb,
                        int N, int K, int ldc, int coff, int4 perm, int act,
                        int nz, long astride, long wstride, long cstride, int coffstride,
                        hipStream_t s, int M = ROWS, int bstride = 0) {
  dim3 grid(M / BM, (N + BN - 1) / BN, nz);
  gemm_kernel<BM, BN><<<grid, 256, 0, s>>>(A, lda, W, bias, C, Cb, N, K, ldc, coff, perm, act,
                                           astride, wstride, cstride, coffstride, bstride);
}

extern "C" void kernel_launch(void* const* d_in, const int* in_sizes, int n_in,
                              void* d_out, int out_size, void* d_ws, size_t ws_size,
                              hipStream_t stream) {
  (void)in_sizes; (void)n_in; (void)out_size; (void)ws_size;
  const float* x        = (const float*)d_in[0];
  const float* norm_g   = (const float*)d_in[1];
  const float* norm_b   = (const float*)d_in[2];
  const float* in_w     = (const float*)d_in[3];
  const float* in_b     = (const float*)d_in[4];
  const float* m_in_w   = (const float*)d_in[5];
  const float* m_conv_w = (const float*)d_in[6];
  const float* m_conv_b = (const float*)d_in[7];
  const float* m_xp_w   = (const float*)d_in[8];
  const float* m_dt_w   = (const float*)d_in[9];
  const float* m_dt_b   = (const float*)d_in[10];
  const float* m_Alog   = (const float*)d_in[11];
  const float* m_D      = (const float*)d_in[12];
  const float* m_out_w  = (const float*)d_in[13];
  const float* f_w1     = (const float*)d_in[14];
  const float* f_b1     = (const float*)d_in[15];
  const float* f_w2     = (const float*)d_in[16];
  const float* f_b2     = (const float*)d_in[17];
  const float* o_w      = (const float*)d_in[18];
  const float* o_b      = (const float*)d_in[19];
  const float* on_g     = (const float*)d_in[20];
  const float* on_b     = (const float*)d_in[21];
  float* out = (float*)d_out;

  // ---- workspace layout ----
  float* ws   = (float*)d_ws;
  float* xs   = ws;                        // 786432 f
  float* dbl  = xs + 786432;               // 720896 f
  float* hseg = dbl + 720896;              // 3145728 f
  float* Sseg = hseg + 3145728;            // 196608 f
  float* bC   = Sseg + 196608;             // 3072 f (pad 4096)
  ushortx* xs_bf  = (ushortx*)(bC + 4096);      // 786432 sh
  ushortx* wbf    = xs_bf + 786432;             // 1394688 sh
  ushortx* WinC   = wbf + 1394688;              // 4*768*192 = 589824 sh
  ushortx* dt_bf  = WinC + 589824;              // 6291456 sh
  ushortx* xz_bf  = dt_bf + 6291456;            // 12582912 sh
  ushortx* xsm_bf = xz_bf + 12582912;           // 6291456 sh (x, then y in place)
  // xz_bf dead after scan -> alias post-scan bf16 buffers into it
  ushortx* fused_bf = xz_bf;                    // 3145728 sh
  ushortx* hdn_bf   = fused_bf + 3145728;       // 1572864 sh
  ushortx* h2_bf    = hdn_bf + 1572864;         // 786432 sh

  // weight offsets in wbf (shorts)
  const unsigned W_MIN = 0, W_XP = 589824, W_OUT = 657408, W_F1 = 952320,
                 W_F2 = 1247232, W_O = 1320960, W_INT = 1357824;   // end 1394688

  int4 p0 = make_int4(0, 0, 0, 0);
  int4 pfwd = make_int4(0, 1, 2, 3);
  int4 pinv = make_int4(0, 1, 2, 4);

  // 0) prep: wcvt + in_wT + input LN + bC
  {
    WcvtArgs a;
    a.src[0] = m_in_w;  a.off[0] = W_MIN; a.n[0] = 589824;
    a.src[1] = m_xp_w;  a.off[1] = W_XP;  a.n[1] = 67584;
    a.src[2] = m_out_w; a.off[2] = W_OUT; a.n[2] = 294912;
    a.src[3] = f_w1;    a.off[3] = W_F1;  a.n[3] = 294912;
    a.src[4] = f_w2;    a.off[4] = W_F2;  a.n[4] = 73728;
    a.src[5] = o_w;     a.off[5] = W_O;   a.n[5] = 36864;
    prep_kernel<<<dim3(1024, 9), 256, 0, stream>>>(
        a, wbf, in_w, W_INT, in_b, bC, x, norm_g, norm_b, xs, xs_bf);
  }
  // 0b) WinC_k = Win_k @ in_w  (768x192 per dir, K=192)
  gemm<64, 64>(wbf + W_MIN, DM, wbf + W_INT, nullptr, nullptr, WinC,
               DM, DM, DM, 0, p0, 0, 4, (long)768 * DM, 0, (long)768 * DM, 0,
               stream, 768);
  // 3) xz_k = perm_k(xs) @ WinC_k^T + bC_k — full-K preload (6 slabs)
  gemm_fullk_kernel<6><<<dim3(ROWS / 64, 768 / 64, 4), 256, 0, stream>>>(
      xs_bf, DM, WinC, bC, xz_bf, 2 * DI, 0, pfwd,
      0, (long)768 * DM, (long)ROWS * 2 * DI, 0, 768);
  // 4) depthwise causal conv + silu (bf16 -> bf16), 4 t per thread
  conv_silu_kernel<<<(16 * 256 * DI) / 256, 256, 0, stream>>>(xz_bf, m_conv_w, m_conv_b, xsm_bf);
  // 5) dbl_k = xsm_k @ Wxp_k^T (N=44, fp32 out)
  gemm<64, 64>(xsm_bf, DI, wbf + W_XP, nullptr, dbl, nullptr, 44, DI, 44, 0, p0, 0,
               4, (long)ROWS * DI, (long)44 * DI, (long)ROWS * 44, 0, stream);
  // 6) dt = softplus(dbl[:,:12] @ Wdt^T + bdt) -> bf16 (standalone, fully parallel)
  dt_kernel<<<(16 * L * DI) / 256, 256, 0, stream>>>(dbl, m_dt_w, m_dt_b, dt_bf);
  // 7) time-segmented selective scan: pass1 -> mid -> pass2 (+gate)
  scan_pass1<<<dim3(DI / 64, 16, SEG), 64, 0, stream>>>(dbl, dt_bf, xsm_bf, m_Alog, hseg, Sseg);
  scan_mid<<<dim3(DI / 64, 16), 64, 0, stream>>>(hseg, Sseg, m_Alog);
  scan_pass2<<<dim3(DI / 64, 16, SEG), 64, 0, stream>>>(dbl, dt_bf, xz_bf, xsm_bf,
                                                        m_Alog, m_D, hseg);
  // 8) out-proj per direction — full-K preload (12 slabs), scatter into fused cols
  gemm_fullk_kernel<12><<<dim3(ROWS / 64, DM / 64, 4), 256, 0, stream>>>(
      xsm_bf, DI, wbf + W_OUT, nullptr, fused_bf, 4 * DM, 0, pinv,
      (long)ROWS * DI, (long)DM * DI, 0, DM, 0);
  // 9) MLP1 (K=768, generic pipelined)
  gemm<64, 64>(fused_bf, 4 * DM, wbf + W_F1, f_b1, nullptr, hdn_bf, 2 * DM, 4 * DM, 2 * DM,
               0, p0, 1, 1, 0, 0, 0, 0, stream); // gelu
  // 9b) MLP2 — full-K preload (12 slabs)
  gemm_fullk_kernel<12><<<dim3(ROWS / 64, DM / 64, 1), 256, 0, stream>>>(
      hdn_bf, 2 * DM, wbf + W_F2, f_b2, h2_bf, DM, 0, p0,
      0, 0, 0, 0, 0);
  // 10+11) fused out-proj + final LN + residual + transposed store
  gemm_ln_kernel<<<64, 256, 0, stream>>>(h2_bf, wbf + W_O, o_b, on_g, on_b, xs, out);
}

// Round 19
// 297.919 us; speedup vs baseline: 1.0730x; 1.0730x over previous
//
#include <hip/hip_runtime.h>
#include <cstddef>

#define DM 192
#define DI 384
#define DS 16
#define DR 12
#define L 1024
#define ROWS 4096   // B*N = 4*1024
#define SEG 32      // time segments for two-pass scan
#define ST  32      // steps per segment

typedef unsigned short ushortx;
typedef short bf16x8 __attribute__((ext_vector_type(8)));
typedef float f32x4  __attribute__((ext_vector_type(4)));

// ---------------- helpers ----------------
__device__ __forceinline__ float wave_sum(float v) {
  #pragma unroll
  for (int off = 32; off > 0; off >>= 1) v += __shfl_xor(v, off);
  return v;
}

__device__ __forceinline__ ushortx f2bf(float x) {   // fp32 -> bf16 RNE
  unsigned u = __float_as_uint(x);
  u += 0x7fffu + ((u >> 16) & 1u);
  return (ushortx)(u >> 16);
}
__device__ __forceinline__ float bf2f(ushortx u) {
  return __uint_as_float(((unsigned)u) << 16);
}

// row permutation within each batch's 1024 rows
__device__ __forceinline__ int map_row(int t, int mode) {
  switch (mode) {
    case 1: return 1023 - t;                                   // flip
    case 2: return ((t & 31) << 5) | (t >> 5);                 // 32x32 transpose
    case 3: { int u = 1023 - t; return ((u & 31) << 5) | (u >> 5); } // perm(flip)
    case 4: return 1023 - (((t & 31) << 5) | (t >> 5));        // flip(perm)
    default: return t;
  }
}

// ---------------- prep: wcvt(y<6) / in_wT(y==6) / input LN(y==7) / bC(y==8) -------------
struct WcvtArgs {
  const float* src[6];
  unsigned int off[6];   // dst offset in shorts
  unsigned int n[6];     // element count
};
__global__ __launch_bounds__(256) void prep_kernel(
    WcvtArgs a, ushortx* __restrict__ dst,
    const float* __restrict__ in_w, unsigned int_off,
    const float* __restrict__ in_b, float* __restrict__ bC,
    const float* __restrict__ x, const float* __restrict__ g,
    const float* __restrict__ b, float* __restrict__ xs, ushortx* __restrict__ xs_bf)
{
  int y = blockIdx.y;
  if (y < 6) {
    int i = (blockIdx.x * 256 + threadIdx.x) * 4;
    if (i < (int)a.n[y]) {
      float4 v = *(const float4*)(a.src[y] + i);
      ushort4 o;
      o.x = f2bf(v.x); o.y = f2bf(v.y); o.z = f2bf(v.z); o.w = f2bf(v.w);
      *(ushort4*)(dst + a.off[y] + i) = o;
    }
    return;
  }
  if (y == 6) {   // in_wT[n][j] = in_w[j][n]; 192*192
    int i = blockIdx.x * 256 + threadIdx.x;
    if (i < DM * DM) {
      int n = i / DM, j = i % DM;
      dst[int_off + i] = f2bf(in_w[(size_t)j * DM + n]);
    }
    return;
  }
  if (y == 8) {   // bC[k][n] = sum_j Win_k[n][j] * in_b[j];  4*768
    int idx = blockIdx.x * 256 + threadIdx.x;
    if (idx < 4 * 768) {
      int k = idx / 768, n = idx % 768;
      const float* wr = a.src[0] + (size_t)k * 768 * DM + (size_t)n * DM;  // m_in_w
      float acc = 0.f;
      for (int j = 0; j < DM; ++j) acc = fmaf(wr[j], in_b[j], acc);
      bC[idx] = acc;
    }
    return;
  }
  // ---- y==7: input layernorm + transpose ----
  if (blockIdx.x >= 1024) return;
  int wave = threadIdx.x >> 6;
  int lane = threadIdx.x & 63;
  int r = blockIdx.x * 4 + wave;          // b*1024 + n
  int bb = r >> 10, n = r & 1023;
  const float* xb = x + (size_t)bb * DM * L + n;
  float v[3];
  float s = 0.f, s2 = 0.f;
  #pragma unroll
  for (int j = 0; j < 3; ++j) {
    int c = lane + j * 64;
    v[j] = xb[(size_t)c * L];
    s += v[j]; s2 += v[j] * v[j];
  }
  s = wave_sum(s); s2 = wave_sum(s2);
  float mean = s * (1.f / DM);
  float var  = s2 * (1.f / DM) - mean * mean;
  float rstd = rsqrtf(var + 1e-5f);
  float* xo = xs + (size_t)r * DM;
  ushortx* xob = xs_bf + (size_t)r * DM;
  #pragma unroll
  for (int j = 0; j < 3; ++j) {
    int c = lane + j * 64;
    float val = (v[j] - mean) * rstd * g[c] + b[c];
    xo[c] = val;
    xob[c] = f2bf(val);
  }
}

// ---------------- full-K-preload GEMM: all NIT*2 loads in flight at t=0 -----------------
// BM=BN=64, K = NIT*32 (<=12 slabs); N multiple of 64 (no guard); bf16 out.
template <int NIT>
__global__ __launch_bounds__(256) void gemm_fullk_kernel(
    const ushortx* __restrict__ A, int lda, const ushortx* __restrict__ W,
    const float* __restrict__ bias, ushortx* __restrict__ Cb,
    int ldc, int coff, int4 perm,
    long astride, long wstride, long cstride, int coffstride, int bstride)
{
  __shared__ __align__(16) short As[2][64][40];
  __shared__ __align__(16) short Bs[2][64][40];

  int z = blockIdx.z;
  A += (size_t)z * astride;
  W += (size_t)z * wstride;
  Cb += (size_t)z * cstride;
  if (bias) bias += (size_t)z * bstride;
  int permMode = (z == 0) ? perm.x : (z == 1) ? perm.y : (z == 2) ? perm.z : perm.w;
  int co = coff + z * coffstride;
  const int K = NIT * 32;

  int tid = threadIdx.x;
  int m0 = blockIdx.x * 64;
  int n0 = blockIdx.y * 64;

  int ar = tid >> 2, ak = (tid & 3) * 8;
  int arow = m0 + ar;
  int amrow = (arow & ~1023) | map_row(arow & 1023, permMode);
  const ushortx* ap = A + (size_t)amrow * lda + ak;
  const ushortx* wp = W + (size_t)(n0 + ar) * K + ak;

  int lane = tid & 63;
  int w = tid >> 6, wm = w >> 1, wn = w & 1;
  int lm = lane & 15, lq = lane >> 4;

  bf16x8 rA[NIT], rB[NIT];
  #pragma unroll
  for (int ki = 0; ki < NIT; ++ki) rA[ki] = *(const bf16x8*)(ap + ki * 32);
  #pragma unroll
  for (int ki = 0; ki < NIT; ++ki) rB[ki] = *(const bf16x8*)(wp + ki * 32);

  f32x4 acc[2][2];
  #pragma unroll
  for (int i = 0; i < 2; ++i)
    #pragma unroll
    for (int j = 0; j < 2; ++j) acc[i][j] = (f32x4){0.f, 0.f, 0.f, 0.f};

  *(bf16x8*)&As[0][ar][ak] = rA[0];
  *(bf16x8*)&Bs[0][ar][ak] = rB[0];
  __syncthreads();

  #pragma unroll
  for (int ki = 0; ki < NIT; ++ki) {
    int cur = ki & 1;
    bf16x8 fa[2], fb[2];
    #pragma unroll
    for (int i = 0; i < 2; ++i)
      fa[i] = *(const bf16x8*)&As[cur][wm * 32 + i * 16 + lm][lq * 8];
    #pragma unroll
    for (int j = 0; j < 2; ++j)
      fb[j] = *(const bf16x8*)&Bs[cur][wn * 32 + j * 16 + lm][lq * 8];
    #pragma unroll
    for (int i = 0; i < 2; ++i)
      #pragma unroll
      for (int j = 0; j < 2; ++j)
        acc[i][j] = __builtin_amdgcn_mfma_f32_16x16x32_bf16(fa[i], fb[j], acc[i][j], 0, 0, 0);
    if (ki + 1 < NIT) {
      int nxt = cur ^ 1;
      *(bf16x8*)&As[nxt][ar][ak] = rA[ki + 1];
      *(bf16x8*)&Bs[nxt][ar][ak] = rB[ki + 1];
      __syncthreads();
    }
  }

  #pragma unroll
  for (int i = 0; i < 2; ++i) {
    #pragma unroll
    for (int r = 0; r < 4; ++r) {
      int row = m0 + wm * 32 + i * 16 + lq * 4 + r;
      #pragma unroll
      for (int j = 0; j < 2; ++j) {
        int n = n0 + wn * 32 + j * 16 + lm;
        float v = acc[i][j][r];
        if (bias) v += bias[n];
        Cb[(size_t)row * ldc + co + n] = f2bf(v);
      }
    }
  }
}

// ---------------- bf16 MFMA GEMM: double-buffered, register-prefetched K-loop ----------
template <int BM, int BN>
__global__ __launch_bounds__(256) void gemm_kernel(
    const ushortx* __restrict__ A, int lda, const ushortx* __restrict__ W,
    const float* __restrict__ bias, float* __restrict__ C, ushortx* __restrict__ Cb,
    int N, int K, int ldc, int coff, int4 perm, int act,
    long astride, long wstride, long cstride, int coffstride, int bstride)
{
  constexpr int MF = BM / 32;
  constexpr int NF = BN / 32;
  constexpr int AR = (BM * 32) / (256 * 8);
  constexpr int BR = (BN * 32) / (256 * 8);
  __shared__ __align__(16) short As[2][BM][40];
  __shared__ __align__(16) short Bs[2][BN][40];

  int z = blockIdx.z;
  A += (size_t)z * astride;
  W += (size_t)z * wstride;
  if (C)  C  += (size_t)z * cstride;
  if (Cb) Cb += (size_t)z * cstride;
  if (bias) bias += (size_t)z * bstride;
  int permMode = (z == 0) ? perm.x : (z == 1) ? perm.y : (z == 2) ? perm.z : perm.w;
  int co = coff + z * coffstride;

  int tid = threadIdx.x;
  int m0 = blockIdx.x * BM;
  int n0 = blockIdx.y * BN;

  int ar, ak;
  if (AR == 2) { ar = tid >> 1; ak = (tid & 1) * 16; }
  else         { ar = tid >> 2; ak = (tid & 3) * 8; }
  int arow = m0 + ar;
  int amrow = (arow & ~1023) | map_row(arow & 1023, permMode);
  const ushortx* ap = A + (size_t)amrow * lda + ak;

  int bn, bk;
  if (BR == 2) { bn = tid >> 1; bk = (tid & 1) * 16; }
  else         { bn = tid >> 2; bk = (tid & 3) * 8; }
  const ushortx* wp = W + (size_t)(n0 + bn) * K + bk;
  bool bok = (n0 + bn) < N;

  int lane = tid & 63;
  int w = tid >> 6, wm = w >> 1, wn = w & 1;
  int lm = lane & 15, lq = lane >> 4;

  f32x4 acc[MF][NF];
  #pragma unroll
  for (int i = 0; i < MF; ++i)
    #pragma unroll
    for (int j = 0; j < NF; ++j) acc[i][j] = (f32x4){0.f, 0.f, 0.f, 0.f};

  const bf16x8 zz = {0, 0, 0, 0, 0, 0, 0, 0};
  bf16x8 ra[AR], rb[BR];

  #pragma unroll
  for (int u = 0; u < AR; ++u) ra[u] = *(const bf16x8*)(ap + u * 8);
  #pragma unroll
  for (int u = 0; u < BR; ++u) rb[u] = bok ? *(const bf16x8*)(wp + u * 8) : zz;
  #pragma unroll
  for (int u = 0; u < AR; ++u) *(bf16x8*)&As[0][ar][ak + u * 8] = ra[u];
  #pragma unroll
  for (int u = 0; u < BR; ++u) *(bf16x8*)&Bs[0][bn][bk + u * 8] = rb[u];
  __syncthreads();

  int niter = K >> 5;
  for (int ki = 0; ki < niter; ++ki) {
    int cur = ki & 1;
    if (ki + 1 < niter) {
      int k0 = (ki + 1) * 32;
      #pragma unroll
      for (int u = 0; u < AR; ++u) ra[u] = *(const bf16x8*)(ap + k0 + u * 8);
      #pragma unroll
      for (int u = 0; u < BR; ++u) rb[u] = bok ? *(const bf16x8*)(wp + k0 + u * 8) : zz;
    }
    bf16x8 fa[MF], fb[NF];
    #pragma unroll
    for (int i = 0; i < MF; ++i)
      fa[i] = *(const bf16x8*)&As[cur][wm * (BM / 2) + i * 16 + lm][lq * 8];
    #pragma unroll
    for (int j = 0; j < NF; ++j)
      fb[j] = *(const bf16x8*)&Bs[cur][wn * (BN / 2) + j * 16 + lm][lq * 8];
    #pragma unroll
    for (int i = 0; i < MF; ++i)
      #pragma unroll
      for (int j = 0; j < NF; ++j)
        acc[i][j] = __builtin_amdgcn_mfma_f32_16x16x32_bf16(fa[i], fb[j], acc[i][j], 0, 0, 0);
    if (ki + 1 < niter) {
      int nxt = cur ^ 1;
      #pragma unroll
      for (int u = 0; u < AR; ++u) *(bf16x8*)&As[nxt][ar][ak + u * 8] = ra[u];
      #pragma unroll
      for (int u = 0; u < BR; ++u) *(bf16x8*)&Bs[nxt][bn][bk + u * 8] = rb[u];
      __syncthreads();
    }
  }

  #pragma unroll
  for (int i = 0; i < MF; ++i) {
    #pragma unroll
    for (int r = 0; r < 4; ++r) {
      int row = m0 + wm * (BM / 2) + i * 16 + lq * 4 + r;
      #pragma unroll
      for (int j = 0; j < NF; ++j) {
        int n = n0 + wn * (BN / 2) + j * 16 + lm;
        if (n < N) {
          float v = acc[i][j][r];
          if (bias) v += bias[n];
          if (act == 1) v = 0.5f * v * (1.f + erff(v * 0.70710678118f));
          if (C)  C [(size_t)row * ldc + co + n] = v;
          if (Cb) Cb[(size_t)row * ldc + co + n] = f2bf(v);
        }
      }
    }
  }
}

// ---------------- fused: out = LN(h2 @ o_w^T + o_b) + xs, transposed store -------------
__global__ __launch_bounds__(256) void gemm_ln_kernel(
    const ushortx* __restrict__ A, const ushortx* __restrict__ W,
    const float* __restrict__ ob, const float* __restrict__ g,
    const float* __restrict__ b, const float* __restrict__ xs,
    float* __restrict__ out)
{
  __shared__ __align__(16) char smem[64 * 200 * 4];
  short* As0 = (short*)smem;              // 64*40
  short* As1 = As0 + 64 * 40;
  short* Bs0 = As1 + 64 * 40;             // 192*40
  short* Bs1 = Bs0 + 192 * 40;
  float* Ct  = (float*)smem;              // 64*200 (after barrier; aliases As/Bs)

  int tid = threadIdx.x;
  int m0 = blockIdx.x * 64;

  int ar = tid >> 2, ak = (tid & 3) * 8;
  const ushortx* ap = A + (size_t)(m0 + ar) * DM + ak;

  int lane = tid & 63;
  int w = tid >> 6, wm = w >> 1, wn = w & 1;
  int lm = lane & 15, lq = lane >> 4;

  f32x4 acc[2][6];
  #pragma unroll
  for (int i = 0; i < 2; ++i)
    #pragma unroll
    for (int j = 0; j < 6; ++j) acc[i][j] = (f32x4){0.f, 0.f, 0.f, 0.f};

  bf16x8 ra, rb[3];
  ra = *(const bf16x8*)ap;
  #pragma unroll
  for (int u = 0; u < 3; ++u) {
    int c = tid + u * 256;
    rb[u] = *(const bf16x8*)(W + (size_t)(c >> 2) * DM + (c & 3) * 8);
  }
  *(bf16x8*)&As0[ar * 40 + ak] = ra;
  #pragma unroll
  for (int u = 0; u < 3; ++u) {
    int c = tid + u * 256;
    *(bf16x8*)&Bs0[(c >> 2) * 40 + (c & 3) * 8] = rb[u];
  }
  __syncthreads();

  const int niter = DM / 32;   // 6
  for (int ki = 0; ki < niter; ++ki) {
    short* Ac = (ki & 1) ? As1 : As0;
    short* Bc = (ki & 1) ? Bs1 : Bs0;
    if (ki + 1 < niter) {
      int k0 = (ki + 1) * 32;
      ra = *(const bf16x8*)(ap + k0);
      #pragma unroll
      for (int u = 0; u < 3; ++u) {
        int c = tid + u * 256;
        rb[u] = *(const bf16x8*)(W + (size_t)(c >> 2) * DM + (c & 3) * 8 + k0);
      }
    }
    bf16x8 fa[2], fb[6];
    #pragma unroll
    for (int i = 0; i < 2; ++i)
      fa[i] = *(const bf16x8*)&Ac[(wm * 32 + i * 16 + lm) * 40 + lq * 8];
    #pragma unroll
    for (int j = 0; j < 6; ++j)
      fb[j] = *(const bf16x8*)&Bc[(wn * 96 + j * 16 + lm) * 40 + lq * 8];
    #pragma unroll
    for (int i = 0; i < 2; ++i)
      #pragma unroll
      for (int j = 0; j < 6; ++j)
        acc[i][j] = __builtin_amdgcn_mfma_f32_16x16x32_bf16(fa[i], fb[j], acc[i][j], 0, 0, 0);
    if (ki + 1 < niter) {
      short* An = (ki & 1) ? As0 : As1;
      short* Bn = (ki & 1) ? Bs0 : Bs1;
      *(bf16x8*)&An[ar * 40 + ak] = ra;
      #pragma unroll
      for (int u = 0; u < 3; ++u) {
        int c = tid + u * 256;
        *(bf16x8*)&Bn[(c >> 2) * 40 + (c & 3) * 8] = rb[u];
      }
    }
    __syncthreads();
  }

  #pragma unroll
  for (int i = 0; i < 2; ++i) {
    #pragma unroll
    for (int r = 0; r < 4; ++r) {
      int row = wm * 32 + i * 16 + lq * 4 + r;
      #pragma unroll
      for (int j = 0; j < 6; ++j) {
        int col = wn * 96 + j * 16 + lm;
        Ct[row * 200 + col] = acc[i][j][r] + ob[col];
      }
    }
  }
  __syncthreads();

  int row = tid >> 2, p = tid & 3;
  const float* base = Ct + row * 200 + p * 48;
  float s = 0.f, s2 = 0.f;
  #pragma unroll
  for (int c = 0; c < 48; ++c) { float v = base[c]; s += v; s2 += v * v; }
  s  += __shfl_xor(s, 1);  s  += __shfl_xor(s, 2);
  s2 += __shfl_xor(s2, 1); s2 += __shfl_xor(s2, 2);
  float mean = s * (1.f / DM);
  float var  = s2 * (1.f / DM) - mean * mean;
  float rstd = rsqrtf(var + 1e-5f);
  int gr = m0 + row, bb = gr >> 10, n = gr & 1023;
  const float* xsr = xs + (size_t)gr * DM + p * 48;
  float* op = out + (size_t)bb * DM * L + n;
  #pragma unroll
  for (int c48 = 0; c48 < 48; ++c48) {
    int c = p * 48 + c48;
    float val = (base[c48] - mean) * rstd * g[c] + b[c] + xsr[c48];
    op[(size_t)c * L] = val;
  }
}

// ---------------- depthwise causal conv (k=4) + bias + silu: 4 t per thread ------------
__global__ __launch_bounds__(256) void conv_silu_kernel(
    const ushortx* __restrict__ xz, const float* __restrict__ cw,
    const float* __restrict__ cb, ushortx* __restrict__ xsm_bf)
{
  int idx = blockIdx.x * 256 + threadIdx.x;   // 16*256*384 total
  int d = idx % DI;
  int rest = idx / DI;
  int tq = rest & 255;
  int seq = rest >> 8;
  int k = seq >> 2;
  int t0 = tq * 4;
  const ushortx* xh = xz + (size_t)seq * L * (2 * DI) + d;
  const float* w = cw + ((size_t)k * DI + d) * 4;
  float w0 = w[0], w1 = w[1], w2 = w[2], w3 = w[3];
  float bias = cb[k * DI + d];
  float in[7];
  #pragma unroll
  for (int j = 0; j < 7; ++j) {
    int t = t0 - 3 + j;
    in[j] = (t >= 0) ? bf2f(xh[(size_t)t * (2 * DI)]) : 0.f;
  }
  ushortx* yo = xsm_bf + ((size_t)seq * L + t0) * DI + d;
  #pragma unroll
  for (int i = 0; i < 4; ++i) {
    float acc = bias;
    acc = fmaf(w0, in[i],     acc);
    acc = fmaf(w1, in[i + 1], acc);
    acc = fmaf(w2, in[i + 2], acc);
    acc = fmaf(w3, in[i + 3], acc);
    float sig = 1.f / (1.f + __expf(-acc));
    yo[(size_t)i * DI] = f2bf(acc * sig);
  }
}

// ---------------- dt = softplus(dbl[:, :12] @ Wdt^T + bdt) -> bf16 ----------------
__global__ __launch_bounds__(256) void dt_kernel(
    const float* __restrict__ dbl, const float* __restrict__ Wdt,
    const float* __restrict__ bdt, ushortx* __restrict__ dt)
{
  int idx = blockIdx.x * 256 + threadIdx.x;   // 16*1024*384
  int d = idx % DI;
  int row = idx / DI;        // seq*1024 + t
  int k = row >> 12;
  const float* dl = dbl + (size_t)row * 44;
  const float* w = Wdt + ((size_t)k * DI + d) * DR;
  float acc = bdt[k * DI + d];
  #pragma unroll
  for (int r = 0; r < DR; ++r) acc = fmaf(w[r], dl[r], acc);
  float v = (acc > 20.f) ? acc : log1pf(__expf(acc));
  dt[idx] = f2bf(v);
}

// ---------------- scan pass 1: per-segment partial scan (lean inner loop) ----------------
__global__ __launch_bounds__(64) void scan_pass1(
    const float* __restrict__ dbl, const ushortx* __restrict__ dt,
    const ushortx* __restrict__ xsm_bf, const float* __restrict__ Alog,
    float* __restrict__ hseg, float* __restrict__ Sseg)
{
  __shared__ __align__(16) float sB[ST][16];
  int seq = blockIdx.y, g = blockIdx.z, k = seq >> 2;
  int d = blockIdx.x * 64 + threadIdx.x;

  const float* bbase = dbl + ((size_t)seq * L + g * ST) * 44 + 12;
  #pragma unroll
  for (int j = 0; j < 2; ++j) {
    int i = threadIdx.x + j * 64;
    int t = i >> 2, q = (i & 3) * 4;
    *(float4*)&sB[t][q] = *(const float4*)(bbase + (size_t)t * 44 + q);
  }
  float A[16];
  const float* alp = Alog + ((size_t)k * DI + d) * DS;
  #pragma unroll
  for (int s = 0; s < 16; ++s) A[s] = -__expf(alp[s]);

  const ushortx* dtp = dt     + ((size_t)seq * L + g * ST) * DI + d;
  const ushortx* xp  = xsm_bf + ((size_t)seq * L + g * ST) * DI + d;
  __syncthreads();

  float h[16];
  #pragma unroll
  for (int s = 0; s < 16; ++s) h[s] = 0.f;
  float sdt = 0.f;
  float rDt[4], rX[4];
  #pragma unroll
  for (int j = 0; j < 4; ++j) {
    rDt[j] = bf2f(dtp[(size_t)j * DI]);
    rX [j] = bf2f(xp [(size_t)j * DI]);
  }

  #pragma unroll 4
  for (int t = 0; t < ST; ++t) {
    float dtv = rDt[t & 3], xv = rX[t & 3];
    if (t + 4 < ST) {
      rDt[t & 3] = bf2f(dtp[(size_t)(t + 4) * DI]);
      rX [t & 3] = bf2f(xp [(size_t)(t + 4) * DI]);
    }
    float dtx = dtv * xv;
    sdt += dtv;
    #pragma unroll
    for (int s = 0; s < 16; ++s) {
      float dA = __expf(dtv * A[s]);
      h[s] = fmaf(dA, h[s], dtx * sB[t][s]);
    }
  }
  float* hp = hseg + (((size_t)seq * SEG + g) * DI + d) * DS;
  #pragma unroll
  for (int s = 0; s < 16; ++s) hp[s] = h[s];
  Sseg[((size_t)seq * SEG + g) * DI + d] = sdt;
}

// ---------------- scan mid: fold segment states serially; hseg[g] <- H_init(g) in place ----
__global__ __launch_bounds__(64) void scan_mid(
    float* __restrict__ hseg, const float* __restrict__ Sseg,
    const float* __restrict__ Alog)
{
  int seq = blockIdx.y, k = seq >> 2;
  int d = blockIdx.x * 64 + threadIdx.x;
  float A[16];
  const float* alp = Alog + ((size_t)k * DI + d) * DS;
  #pragma unroll
  for (int s = 0; s < 16; ++s) A[s] = -__expf(alp[s]);
  float h[16];
  #pragma unroll
  for (int s = 0; s < 16; ++s) h[s] = 0.f;
  for (int g = 0; g < SEG; ++g) {
    float* hp = hseg + (((size_t)seq * SEG + g) * DI + d) * DS;
    float Sg = Sseg[((size_t)seq * SEG + g) * DI + d];
    float tmp[16];
    #pragma unroll
    for (int s = 0; s < 16; ++s) tmp[s] = hp[s];
    #pragma unroll
    for (int s = 0; s < 16; ++s) hp[s] = h[s];
    #pragma unroll
    for (int s = 0; s < 16; ++s)
      h[s] = fmaf(h[s], __expf(A[s] * Sg), tmp[s]);
  }
}

// ---------------- scan pass 2: init from hseg + scan + D skip + gate (lean loop) ---------
__global__ __launch_bounds__(64) void scan_pass2(
    const float* __restrict__ dbl, const ushortx* __restrict__ dt,
    const ushortx* __restrict__ xz,
    ushortx* __restrict__ xy,       // x in / y out (in place)
    const float* __restrict__ Alog, const float* __restrict__ Dp,
    const float* __restrict__ hseg)
{
  __shared__ __align__(16) float sBC[ST][32];
  int seq = blockIdx.y, g = blockIdx.z, k = seq >> 2;
  int d = blockIdx.x * 64 + threadIdx.x;

  const float* bcbase = dbl + ((size_t)seq * L + g * ST) * 44 + 12;
  #pragma unroll
  for (int j = 0; j < 4; ++j) {
    int i = threadIdx.x + j * 64;
    int t = i >> 3, q = (i & 7) * 4;
    *(float4*)&sBC[t][q] = *(const float4*)(bcbase + (size_t)t * 44 + q);
  }
  float A[16];
  const float* alp = Alog + ((size_t)k * DI + d) * DS;
  #pragma unroll
  for (int s = 0; s < 16; ++s) A[s] = -__expf(alp[s]);
  float Dv = Dp[k * DI + d];

  float h[16];
  {
    const float* hp = hseg + (((size_t)seq * SEG + g) * DI + d) * DS;
    #pragma unroll
    for (int s = 0; s < 16; ++s) h[s] = hp[s];
  }

  const ushortx* dtp = dt + ((size_t)seq * L + g * ST) * DI + d;
  const ushortx* zp  = xz + ((size_t)seq * L + g * ST) * (2 * DI) + DI + d;
  ushortx*       yp  = xy + ((size_t)seq * L + g * ST) * DI + d;
  __syncthreads();

  float rDt[4], rX[4], rZ[4];
  #pragma unroll
  for (int j = 0; j < 4; ++j) {
    rDt[j] = bf2f(dtp[(size_t)j * DI]);
    rX [j] = bf2f(yp [(size_t)j * DI]);
    rZ [j] = bf2f(zp [(size_t)j * (2 * DI)]);
  }

  #pragma unroll 4
  for (int t = 0; t < ST; ++t) {
    float dtv = rDt[t & 3], xv = rX[t & 3], zv = rZ[t & 3];
    if (t + 4 < ST) {
      rDt[t & 3] = bf2f(dtp[(size_t)(t + 4) * DI]);
      rX [t & 3] = bf2f(yp [(size_t)(t + 4) * DI]);
      rZ [t & 3] = bf2f(zp [(size_t)(t + 4) * (2 * DI)]);
    }
    float dtx = dtv * xv;
    float y = 0.f;
    #pragma unroll
    for (int s = 0; s < 16; ++s) {
      float dA = __expf(dtv * A[s]);
      h[s] = fmaf(dA, h[s], dtx * sBC[t][s]);
      y = fmaf(h[s], sBC[t][16 + s], y);
    }
    y = fmaf(Dv, xv, y);
    float sig = 1.f / (1.f + __expf(-zv));
    yp[(size_t)t * DI] = f2bf(y * (zv * sig));
  }
}

// ---------------- host side ----------------
template <int BM, int BN>
static inline void gemm(const ushortx* A, int lda, const ushortx* W, const float* bias,
                        float* C, ushortx* Cb,
                        int N, int K, int ldc, int coff, int4 perm, int act,
                        int nz, long astride, long wstride, long cstride, int coffstride,
                        hipStream_t s, int M = ROWS, int bstride = 0) {
  dim3 grid(M / BM, (N + BN - 1) / BN, nz);
  gemm_kernel<BM, BN><<<grid, 256, 0, s>>>(A, lda, W, bias, C, Cb, N, K, ldc, coff, perm, act,
                                           astride, wstride, cstride, coffstride, bstride);
}

extern "C" void kernel_launch(void* const* d_in, const int* in_sizes, int n_in,
                              void* d_out, int out_size, void* d_ws, size_t ws_size,
                              hipStream_t stream) {
  (void)in_sizes; (void)n_in; (void)out_size; (void)ws_size;
  const float* x        = (const float*)d_in[0];
  const float* norm_g   = (const float*)d_in[1];
  const float* norm_b   = (const float*)d_in[2];
  const float* in_w     = (const float*)d_in[3];
  const float* in_b     = (const float*)d_in[4];
  const float* m_in_w   = (const float*)d_in[5];
  const float* m_conv_w = (const float*)d_in[6];
  const float* m_conv_b = (const float*)d_in[7];
  const float* m_xp_w   = (const float*)d_in[8];
  const float* m_dt_w   = (const float*)d_in[9];
  const float* m_dt_b   = (const float*)d_in[10];
  const float* m_Alog   = (const float*)d_in[11];
  const float* m_D      = (const float*)d_in[12];
  const float* m_out_w  = (const float*)d_in[13];
  const float* f_w1     = (const float*)d_in[14];
  const float* f_b1     = (const float*)d_in[15];
  const float* f_w2     = (const float*)d_in[16];
  const float* f_b2     = (const float*)d_in[17];
  const float* o_w      = (const float*)d_in[18];
  const float* o_b      = (const float*)d_in[19];
  const float* on_g     = (const float*)d_in[20];
  const float* on_b     = (const float*)d_in[21];
  float* out = (float*)d_out;

  // ---- workspace layout ----
  float* ws   = (float*)d_ws;
  float* xs   = ws;                        // 786432 f
  float* dbl  = xs + 786432;               // 720896 f
  float* hseg = dbl + 720896;              // 3145728 f
  float* Sseg = hseg + 3145728;            // 196608 f
  float* bC   = Sseg + 196608;             // 3072 f (pad 4096)
  ushortx* xs_bf  = (ushortx*)(bC + 4096);      // 786432 sh
  ushortx* wbf    = xs_bf + 786432;             // 1394688 sh
  ushortx* WinC   = wbf + 1394688;              // 4*768*192 = 589824 sh
  ushortx* dt_bf  = WinC + 589824;              // 6291456 sh
  ushortx* xz_bf  = dt_bf + 6291456;            // 12582912 sh
  ushortx* xsm_bf = xz_bf + 12582912;           // 6291456 sh (x, then y in place)
  // xz_bf dead after scan -> alias post-scan bf16 buffers into it
  ushortx* fused_bf = xz_bf;                    // 3145728 sh
  ushortx* hdn_bf   = fused_bf + 3145728;       // 1572864 sh
  ushortx* h2_bf    = hdn_bf + 1572864;         // 786432 sh

  // weight offsets in wbf (shorts)
  const unsigned W_MIN = 0, W_XP = 589824, W_OUT = 657408, W_F1 = 952320,
                 W_F2 = 1247232, W_O = 1320960, W_INT = 1357824;   // end 1394688

  int4 p0 = make_int4(0, 0, 0, 0);
  int4 pfwd = make_int4(0, 1, 2, 3);
  int4 pinv = make_int4(0, 1, 2, 4);

  // 0) prep: wcvt + in_wT + input LN + bC
  {
    WcvtArgs a;
    a.src[0] = m_in_w;  a.off[0] = W_MIN; a.n[0] = 589824;
    a.src[1] = m_xp_w;  a.off[1] = W_XP;  a.n[1] = 67584;
    a.src[2] = m_out_w; a.off[2] = W_OUT; a.n[2] = 294912;
    a.src[3] = f_w1;    a.off[3] = W_F1;  a.n[3] = 294912;
    a.src[4] = f_w2;    a.off[4] = W_F2;  a.n[4] = 73728;
    a.src[5] = o_w;     a.off[5] = W_O;   a.n[5] = 36864;
    prep_kernel<<<dim3(1024, 9), 256, 0, stream>>>(
        a, wbf, in_w, W_INT, in_b, bC, x, norm_g, norm_b, xs, xs_bf);
  }
  // 0b) WinC_k = Win_k @ in_w  (768x192 per dir, K=192)
  gemm<64, 64>(wbf + W_MIN, DM, wbf + W_INT, nullptr, nullptr, WinC,
               DM, DM, DM, 0, p0, 0, 4, (long)768 * DM, 0, (long)768 * DM, 0,
               stream, 768);
  // 3) xz_k = perm_k(xs) @ WinC_k^T + bC_k — full-K preload (6 slabs)
  gemm_fullk_kernel<6><<<dim3(ROWS / 64, 768 / 64, 4), 256, 0, stream>>>(
      xs_bf, DM, WinC, bC, xz_bf, 2 * DI, 0, pfwd,
      0, (long)768 * DM, (long)ROWS * 2 * DI, 0, 768);
  // 4) depthwise causal conv + silu (bf16 -> bf16), 4 t per thread
  conv_silu_kernel<<<(16 * 256 * DI) / 256, 256, 0, stream>>>(xz_bf, m_conv_w, m_conv_b, xsm_bf);
  // 5) dbl_k = xsm_k @ Wxp_k^T (N=44, fp32 out)
  gemm<64, 64>(xsm_bf, DI, wbf + W_XP, nullptr, dbl, nullptr, 44, DI, 44, 0, p0, 0,
               4, (long)ROWS * DI, (long)44 * DI, (long)ROWS * 44, 0, stream);
  // 6) dt = softplus(dbl[:,:12] @ Wdt^T + bdt) -> bf16 (standalone, fully parallel)
  dt_kernel<<<(16 * L * DI) / 256, 256, 0, stream>>>(dbl, m_dt_w, m_dt_b, dt_bf);
  // 7) time-segmented selective scan: pass1 -> mid -> pass2 (+gate)
  scan_pass1<<<dim3(DI / 64, 16, SEG), 64, 0, stream>>>(dbl, dt_bf, xsm_bf, m_Alog, hseg, Sseg);
  scan_mid<<<dim3(DI / 64, 16), 64, 0, stream>>>(hseg, Sseg, m_Alog);
  scan_pass2<<<dim3(DI / 64, 16, SEG), 64, 0, stream>>>(dbl, dt_bf, xz_bf, xsm_bf,
                                                        m_Alog, m_D, hseg);
  // 8) out-proj per direction — full-K preload (12 slabs), scatter into fused cols
  gemm_fullk_kernel<12><<<dim3(ROWS / 64, DM / 64, 4), 256, 0, stream>>>(
      xsm_bf, DI, wbf + W_OUT, nullptr, fused_bf, 4 * DM, 0, pinv,
      (long)ROWS * DI, (long)DM * DI, 0, DM, 0);
  // 9) MLP1 (K=768, generic pipelined)
  gemm<64, 64>(fused_bf, 4 * DM, wbf + W_F1, f_b1, nullptr, hdn_bf, 2 * DM, 4 * DM, 2 * DM,
               0, p0, 1, 1, 0, 0, 0, 0, stream); // gelu
  // 9b) MLP2 — full-K preload (12 slabs)
  gemm_fullk_kernel<12><<<dim3(ROWS / 64, DM / 64, 1), 256, 0, stream>>>(
      hdn_bf, 2 * DM, wbf + W_F2, f_b2, h2_bf, DM, 0, p0,
      0, 0, 0, 0, 0);
  // 10+11) fused out-proj + final LN + residual + transposed store
  gemm_ln_kernel<<<64, 256, 0, stream>>>(h2_bf, wbf + W_O, o_b, on_g, on_b, xs, out);
}